// Round 2
// baseline (83.292 us; speedup 1.0000x reference)
//
#include <hip/hip_runtime.h>
#include <math.h>

// Problem: keypoints [B,3,M] f32, pc [B,3,N] f32 -> mean over (b,m) of
// min_n ||k - p||.  Key algebra: ||k-p||^2 = k2 - 2*(dot - 0.5*p2), so with
// hp = -0.5*p2 precomputed per point, min_p d2 = k2 - 2*max_p u where
// u = kx*px + ky*py + kz*pz + hp  -> 3 FMA + 1 max per pair (VALU floor ~7us).
#define BATCH 4
#define M 1024
#define NPTS 32768
#define NSPLIT 128                 // pc chunks per batch
#define CHUNK (NPTS / NSPLIT)      // 256 points per block
#define KPT 4                      // keypoints per thread (256*4 = 1024 = M)
#define TPB 256
#define RBLOCKS 16                 // reduce kernel blocks (16*256 = 4096 = B*M)

// ws layout:
//   float4 q[BATCH*NPTS]        @ 0                  (2 MB)  {x,y,z,hp}
//   float  d2p[NSPLIT][B*M]     @ 2 MB               (2 MB)  per-chunk min d2
//   float  gsum                 @ 4 MB
//   unsigned counter            @ 4 MB + 4
#define Q_OFF      0
#define D2P_OFF    (2u << 20)
#define GSUM_OFF   (4u << 20)
#define CNT_OFF    ((4u << 20) + 4u)

// Kernel 1: build interleaved wave-uniform point array + zero the reduce state.
__global__ __launch_bounds__(256) void p2p_prep(
        const float* __restrict__ pc, float4* __restrict__ q,
        float* __restrict__ gsum, unsigned* __restrict__ counter) {
    int i = blockIdx.x * 256 + threadIdx.x;       // [0, BATCH*NPTS)
    int b = i >> 15;                              // /NPTS (pow2)
    int n = i & (NPTS - 1);
    const float* p = pc + (size_t)b * 3 * NPTS;
    float x = p[n], y = p[NPTS + n], z = p[2 * NPTS + n];
    float hp = -0.5f * fmaf(x, x, fmaf(y, y, z * z));
    q[i] = make_float4(x, y, z, hp);
    if (i == 0) { *gsum = 0.f; *counter = 0u; }
}

// Kernel 2: the hot loop. Point data read via uniform loads (scalar path),
// keypoints live in registers; 3 FMA + max per pair.
__global__ __launch_bounds__(TPB) void p2p_main(
        const float* __restrict__ kp, const float4* __restrict__ q,
        float* __restrict__ d2p) {
    const int b = blockIdx.x / NSPLIT;
    const int c = blockIdx.x % NSPLIT;
    const int t = threadIdx.x;

    const float4* qc = q + b * NPTS + c * CHUNK;  // wave-uniform pointer
    const float* kpb = kp + (size_t)b * 3 * M;

    float kx[KPT], ky[KPT], kz[KPT], k2[KPT], md[KPT];
#pragma unroll
    for (int k = 0; k < KPT; ++k) {
        int m = t + k * TPB;
        kx[k] = kpb[m];
        ky[k] = kpb[M + m];
        kz[k] = kpb[2 * M + m];
        k2[k] = fmaf(kx[k], kx[k], fmaf(ky[k], ky[k], kz[k] * kz[k]));
        md[k] = -INFINITY;                        // maximizing u
    }

#pragma unroll 2
    for (int j = 0; j < CHUNK; j += 4) {
        // Uniform (per-wave constant) loads -> s_load_dwordx4, no LDS needed.
        float4 q0 = qc[j + 0];
        float4 q1 = qc[j + 1];
        float4 q2 = qc[j + 2];
        float4 q3 = qc[j + 3];
#pragma unroll
        for (int k = 0; k < KPT; ++k) {
            float v0 = fmaf(kx[k], q0.x, fmaf(ky[k], q0.y, fmaf(kz[k], q0.z, q0.w)));
            float v1 = fmaf(kx[k], q1.x, fmaf(ky[k], q1.y, fmaf(kz[k], q1.z, q1.w)));
            float v2 = fmaf(kx[k], q2.x, fmaf(ky[k], q2.y, fmaf(kz[k], q2.z, q2.w)));
            float v3 = fmaf(kx[k], q3.x, fmaf(ky[k], q3.y, fmaf(kz[k], q3.z, q3.w)));
            // fmax tree -> compiler can fuse into v_max3
            md[k] = fmaxf(md[k], fmaxf(fmaxf(v0, v1), fmaxf(v2, v3)));
        }
    }

#pragma unroll
    for (int k = 0; k < KPT; ++k) {
        // min d2 over this chunk = k2 - 2*max(u); clamp tiny negatives.
        float d2 = fmaxf(fmaf(-2.f, md[k], k2[k]), 0.f);
        d2p[c * (BATCH * M) + b * M + t + k * TPB] = d2;  // coalesced per k
    }
}

// Kernel 3: min over chunks, sqrt, global mean with fence+ticket finish.
__global__ __launch_bounds__(256) void p2p_reduce(
        const float* __restrict__ d2p, float* __restrict__ gsum,
        unsigned* __restrict__ counter, float* __restrict__ out) {
    const int i = blockIdx.x * 256 + threadIdx.x;   // [0, B*M)
    float m0 = INFINITY, m1 = INFINITY;
#pragma unroll 4
    for (int c = 0; c < NSPLIT; c += 2) {
        m0 = fminf(m0, d2p[(c + 0) * (BATCH * M) + i]);
        m1 = fminf(m1, d2p[(c + 1) * (BATCH * M) + i]);
    }
    float s = sqrtf(fminf(m0, m1));
#pragma unroll
    for (int off = 32; off > 0; off >>= 1) s += __shfl_down(s, off, 64);
    __shared__ float sb[4];
    if ((threadIdx.x & 63) == 0) sb[threadIdx.x >> 6] = s;
    __syncthreads();
    if (threadIdx.x == 0) {
        float bsum = sb[0] + sb[1] + sb[2] + sb[3];
        atomicAdd(gsum, bsum);           // device-scope, coherent point
        __threadfence();                 // order gsum-add before ticket
        unsigned tk = atomicAdd(counter, 1u);
        if (tk == RBLOCKS - 1) {
            float total = atomicAdd(gsum, 0.0f);  // RMW read at coherent point
            out[0] = total / (float)(BATCH * M);
        }
    }
}

extern "C" void kernel_launch(void* const* d_in, const int* in_sizes, int n_in,
                              void* d_out, int out_size, void* d_ws, size_t ws_size,
                              hipStream_t stream) {
    const float* kp = (const float*)d_in[0];   // [B,3,M]
    const float* pc = (const float*)d_in[1];   // [B,3,N]
    float* out = (float*)d_out;
    char* ws = (char*)d_ws;
    float4* q = (float4*)(ws + Q_OFF);
    float* d2p = (float*)(ws + D2P_OFF);
    float* gsum = (float*)(ws + GSUM_OFF);
    unsigned* counter = (unsigned*)(ws + CNT_OFF);

    p2p_prep<<<BATCH * NPTS / 256, 256, 0, stream>>>(pc, q, gsum, counter);
    p2p_main<<<BATCH * NSPLIT, TPB, 0, stream>>>(kp, q, d2p);
    p2p_reduce<<<RBLOCKS, 256, 0, stream>>>(d2p, gsum, counter, out);
}

// Round 3
// 78.174 us; speedup vs baseline: 1.0655x; 1.0655x over previous
//
#include <hip/hip_runtime.h>
#include <math.h>

// Problem: keypoints [B,3,M] f32, pc [B,3,N] f32 -> mean over (b,m) of
// min_n ||k - p||.  Algebra: with hp = -0.5*(x^2+y^2+z^2) per point,
// min_p d2 = k2 - 2*max_p (kx*x + ky*y + kz*z + hp)  -> 3 FMA + max per pair,
// packed two-points-at-a-time with v_pk_fma_f32 -> ~2 VALU instr per pair.
#define BATCH 4
#define M 1024
#define NPTS 32768
#define NSPLIT 256                 // pc chunks per batch
#define CHUNK (NPTS / NSPLIT)      // 128 points per block
#define KPT 4                      // keypoints per thread (256*4 = 1024 = M)
#define TPB 256
#define RBLOCKS 16                 // reduce kernel blocks (16*256 = 4096 = B*M)

// ws layout:
//   float  d2p[NSPLIT][B*M]  @ 0      (4 MB)  per-chunk min d2
//   float  gsum              @ 4 MB
//   unsigned counter         @ 4 MB + 4
#define D2P_OFF    0
#define GSUM_OFF   (4u << 20)
#define CNT_OFF    ((4u << 20) + 4u)

typedef float v2f __attribute__((ext_vector_type(2)));

__device__ inline v2f pk_fma(v2f a, v2f b, v2f c) {
    v2f d;
    asm("v_pk_fma_f32 %0, %1, %2, %3" : "=v"(d) : "v"(a), "v"(b), "v"(c));
    return d;
}

// Kernel 1: the hot loop. grid = BATCH*NSPLIT = 1024 blocks (4/CU).
__global__ __launch_bounds__(TPB) void p2p_main(
        const float* __restrict__ kp, const float* __restrict__ pc,
        float* __restrict__ d2p, float* __restrict__ gsum,
        unsigned* __restrict__ counter) {
    __shared__ __align__(16) float qx[CHUNK];
    __shared__ __align__(16) float qy[CHUNK];
    __shared__ __align__(16) float qz[CHUNK];
    __shared__ __align__(16) float qh[CHUNK];

    const int b = blockIdx.x / NSPLIT;
    const int c = blockIdx.x % NSPLIT;
    const int t = threadIdx.x;

    // Zero the reduce-state for kernel 2 (ws is poisoned before every call).
    if (blockIdx.x == 0 && t == 0) { *gsum = 0.f; *counter = 0u; }

    // Stage this block's 128 pc points into LDS (SoA) + precompute hp.
    const float* pcb = pc + (size_t)b * 3 * NPTS + c * CHUNK;
    if (t < CHUNK) {
        float x = pcb[t], y = pcb[NPTS + t], z = pcb[2 * NPTS + t];
        qx[t] = x; qy[t] = y; qz[t] = z;
        qh[t] = -0.5f * fmaf(x, x, fmaf(y, y, z * z));
    }

    // KPT keypoints per thread, broadcast into packed pairs.
    const float* kpb = kp + (size_t)b * 3 * M;
    v2f kx2[KPT], ky2[KPT], kz2[KPT];
    float k2[KPT], md[KPT];
#pragma unroll
    for (int k = 0; k < KPT; ++k) {
        int m = t + k * TPB;
        float x = kpb[m], y = kpb[M + m], z = kpb[2 * M + m];
        kx2[k] = (v2f){x, x};
        ky2[k] = (v2f){y, y};
        kz2[k] = (v2f){z, z};
        k2[k] = fmaf(x, x, fmaf(y, y, z * z));
        md[k] = -INFINITY;          // maximizing u
    }
    __syncthreads();

    // 4 points per iter: 4 broadcast ds_read_b128 + KPT*(6 pk_fma + 2 max3).
#pragma unroll 4
    for (int j = 0; j < CHUNK; j += 4) {
        float4 X = *(const float4*)&qx[j];
        float4 Y = *(const float4*)&qy[j];
        float4 Z = *(const float4*)&qz[j];
        float4 H = *(const float4*)&qh[j];
        v2f X01 = {X.x, X.y}, X23 = {X.z, X.w};
        v2f Y01 = {Y.x, Y.y}, Y23 = {Y.z, Y.w};
        v2f Z01 = {Z.x, Z.y}, Z23 = {Z.z, Z.w};
        v2f H01 = {H.x, H.y}, H23 = {H.z, H.w};
#pragma unroll
        for (int k = 0; k < KPT; ++k) {
            v2f u01 = pk_fma(kx2[k], X01, pk_fma(ky2[k], Y01, pk_fma(kz2[k], Z01, H01)));
            v2f u23 = pk_fma(kx2[k], X23, pk_fma(ky2[k], Y23, pk_fma(kz2[k], Z23, H23)));
            // two v_max3_f32:
            md[k] = fmaxf(fmaxf(md[k], u01.x), u01.y);
            md[k] = fmaxf(fmaxf(md[k], u23.x), u23.y);
        }
    }

#pragma unroll
    for (int k = 0; k < KPT; ++k) {
        float d2 = fmaxf(fmaf(-2.f, md[k], k2[k]), 0.f);
        d2p[c * (BATCH * M) + b * M + t + k * TPB] = d2;   // coalesced
    }
}

// Kernel 2: min over chunks, sqrt, global mean with fence+ticket finish.
__global__ __launch_bounds__(256) void p2p_reduce(
        const float* __restrict__ d2p, float* __restrict__ gsum,
        unsigned* __restrict__ counter, float* __restrict__ out) {
    const int i = blockIdx.x * 256 + threadIdx.x;   // [0, B*M)
    float m0 = INFINITY, m1 = INFINITY, m2 = INFINITY, m3 = INFINITY;
#pragma unroll 2
    for (int c = 0; c < NSPLIT; c += 4) {
        m0 = fminf(m0, d2p[(c + 0) * (BATCH * M) + i]);
        m1 = fminf(m1, d2p[(c + 1) * (BATCH * M) + i]);
        m2 = fminf(m2, d2p[(c + 2) * (BATCH * M) + i]);
        m3 = fminf(m3, d2p[(c + 3) * (BATCH * M) + i]);
    }
    float s = sqrtf(fminf(fminf(m0, m1), fminf(m2, m3)));
#pragma unroll
    for (int off = 32; off > 0; off >>= 1) s += __shfl_down(s, off, 64);
    __shared__ float sb[4];
    if ((threadIdx.x & 63) == 0) sb[threadIdx.x >> 6] = s;
    __syncthreads();
    if (threadIdx.x == 0) {
        float bsum = sb[0] + sb[1] + sb[2] + sb[3];
        atomicAdd(gsum, bsum);           // device-scope
        __threadfence();
        unsigned tk = atomicAdd(counter, 1u);
        if (tk == RBLOCKS - 1) {
            float total = atomicAdd(gsum, 0.0f);  // coherent read-back
            out[0] = total / (float)(BATCH * M);
        }
    }
}

extern "C" void kernel_launch(void* const* d_in, const int* in_sizes, int n_in,
                              void* d_out, int out_size, void* d_ws, size_t ws_size,
                              hipStream_t stream) {
    const float* kp = (const float*)d_in[0];   // [B,3,M]
    const float* pc = (const float*)d_in[1];   // [B,3,N]
    float* out = (float*)d_out;
    char* ws = (char*)d_ws;
    float* d2p = (float*)(ws + D2P_OFF);
    float* gsum = (float*)(ws + GSUM_OFF);
    unsigned* counter = (unsigned*)(ws + CNT_OFF);

    p2p_main<<<BATCH * NSPLIT, TPB, 0, stream>>>(kp, pc, d2p, gsum, counter);
    p2p_reduce<<<RBLOCKS, 256, 0, stream>>>(d2p, gsum, counter, out);
}